// Round 5
// baseline (6362.855 us; speedup 1.0000x reference)
//
#include <hip/hip_runtime.h>
#include <math.h>

#define BQ 32
#define TQ 512
#define DQ 768
#define KQ 256
#define HQ 512
#define G4 2048
#define NWG 512    // 8 groups x 64 WGs
#define NTHR 256
#define NBG 4      // batches per group
#define PROW 1028  // broadcast row: h[0:512) | hbar[512:1024) | pad

typedef float f32x4 __attribute__((ext_vector_type(4)));

__device__ __forceinline__ void waitcnt0() {
  asm volatile("s_waitcnt vmcnt(0) lgkmcnt(0)" ::: "memory");
}
__device__ __forceinline__ void st_agent(float* p, float v) {
  asm volatile("global_store_dword %0, %1, off sc0 sc1" :: "v"(p), "v"(v) : "memory");
}
__device__ __forceinline__ int ld_flag(const int* p) {
  int v;
  asm volatile("global_load_dword %0, %1, off sc0 sc1\ns_waitcnt vmcnt(0)"
               : "=v"(v) : "v"(p) : "memory");
  return v;
}
__device__ __forceinline__ f32x4 ldx4(const float* p) {
  f32x4 v;
  asm volatile("global_load_dwordx4 %0, %1, off sc0 sc1" : "=v"(v) : "v"(p) : "memory");
  return v;
}
__device__ __forceinline__ void wg_wait(const int* flags, int target) {
  const int lane = threadIdx.x & 63;
  for (;;) {
    int v = ld_flag(flags + lane);
    if (__all(v >= target)) break;
    __builtin_amdgcn_s_sleep(1);
  }
  __syncthreads();
}
__device__ __forceinline__ float sigm(float x) { return 1.f / (1.f + __expf(-x)); }

// ---------------- P1: Gram matrix G[b][t][tau] = x_t . x_tau ----------------
__global__ void __launch_bounds__(256) gram_k(const float* __restrict__ X,
                                              float* __restrict__ Gm) {
  __shared__ __align__(16) float As[64 * 33];
  __shared__ __align__(16) float Bs[64 * 33];
  const int bid = blockIdx.x;
  const int b = blockIdx.y;
  int I = 0, base = 0;
  while (base + I + 1 <= bid) { base += I + 1; ++I; }
  const int J = bid - base;
  const int t0 = I * 64, u0 = J * 64;
  const float* Xb = X + (size_t)b * TQ * DQ;
  const int ty = threadIdx.x >> 4, tx = threadIdx.x & 15;
  const int sc = threadIdx.x & 31, sr = threadIdx.x >> 5;
  float acc[4][4];
#pragma unroll
  for (int i = 0; i < 4; ++i)
#pragma unroll
    for (int j = 0; j < 4; ++j) acc[i][j] = 0.f;
  for (int k0 = 0; k0 < DQ; k0 += 32) {
#pragma unroll
    for (int rr = 0; rr < 8; ++rr) {
      const int r = rr * 8 + sr;
      As[r * 33 + sc] = Xb[(size_t)(t0 + r) * DQ + k0 + sc];
      Bs[r * 33 + sc] = Xb[(size_t)(u0 + r) * DQ + k0 + sc];
    }
    __syncthreads();
#pragma unroll
    for (int k = 0; k < 32; ++k) {
      float av[4], bv[4];
#pragma unroll
      for (int i = 0; i < 4; ++i) av[i] = As[(ty * 4 + i) * 33 + k];
#pragma unroll
      for (int j = 0; j < 4; ++j) bv[j] = Bs[(tx * 4 + j) * 33 + k];
#pragma unroll
      for (int i = 0; i < 4; ++i)
#pragma unroll
        for (int j = 0; j < 4; ++j) acc[i][j] += av[i] * bv[j];
    }
    __syncthreads();
  }
  float* gb = Gm + (size_t)b * TQ * TQ;
#pragma unroll
  for (int i = 0; i < 4; ++i) {
    f32x4 o;
    o.x = acc[i][0]; o.y = acc[i][1]; o.z = acc[i][2]; o.w = acc[i][3];
    *(f32x4*)&gb[(size_t)(t0 + ty * 4 + i) * TQ + u0 + tx * 4] = o;
  }
}

// ---------------- P2: row softmax (tau < t) in place + S[b][t] --------------
__global__ void __launch_bounds__(256) smax_k(float* __restrict__ Gm,
                                              float* __restrict__ Sv,
                                              const float* __restrict__ cgp,
                                              const float* __restrict__ cbp) {
  const int t = blockIdx.x + 1;
  const int b = blockIdx.y;
  const int tid = threadIdx.x;
  const int lane = tid & 63;
  const int wv = tid >> 6;
  __shared__ float row[TQ];
  __shared__ float r1[4], r2[4], r3[4];
  float* R = Gm + ((size_t)b * TQ + t) * TQ;
  const float cg = cgp[0], cb = cbp[0];
  for (int i = tid; i < t; i += 256) row[i] = R[i];
  __syncthreads();
  float m = -3e38f;
  for (int i = tid; i < t; i += 256) m = fmaxf(m, row[i]);
#pragma unroll
  for (int k = 1; k < 64; k <<= 1) m = fmaxf(m, __shfl_xor(m, k));
  if (lane == 0) r1[wv] = m;
  __syncthreads();
  m = fmaxf(fmaxf(r1[0], r1[1]), fmaxf(r1[2], r1[3]));
  float s = 0.f, sck = 0.f;
  for (int i = tid; i < t; i += 256) {
    const float r = row[i];
    const float e = __expf(r - m);
    const float ck = 1.f / (1.f + __expf(-(r * cg + cb)));
    row[i] = e; s += e; sck += e * ck;
  }
#pragma unroll
  for (int k = 1; k < 64; k <<= 1) { s += __shfl_xor(s, k); sck += __shfl_xor(sck, k); }
  if (lane == 0) { r2[wv] = s; r3[wv] = sck; }
  __syncthreads();
  s = r2[0] + r2[1] + r2[2] + r2[3];
  sck = r3[0] + r3[1] + r3[2] + r3[3];
  const float inv = 1.f / s;
  for (int i = tid; i < t; i += 256) R[i] = row[i] * inv;
  if (tid == 0) Sv[(size_t)b * TQ + t] = sck * inv;
}

// ---------------- P3: Wcomb[u][col] = sum_k Wkey[u][k] * Wx[k][col] ---------
__global__ void __launch_bounds__(256) wcomb_k(const float* __restrict__ Wkey,
                                               const float* __restrict__ Wx,
                                               float* __restrict__ Wc) {
  __shared__ __align__(16) float As[64 * 33];  // [u][k]
  __shared__ __align__(16) float Bs[64 * 33];  // [col][k]
  const int c0 = blockIdx.x * 64, u0 = blockIdx.y * 64;
  const int ty = threadIdx.x >> 4, tx = threadIdx.x & 15;
  const int sc = threadIdx.x & 31, sr = threadIdx.x >> 5;
  float acc[4][4];
#pragma unroll
  for (int i = 0; i < 4; ++i)
#pragma unroll
    for (int j = 0; j < 4; ++j) acc[i][j] = 0.f;
  for (int k0 = 0; k0 < KQ; k0 += 32) {
#pragma unroll
    for (int rr = 0; rr < 8; ++rr) {
      const int r = rr * 8 + sr;
      As[r * 33 + sc] = Wkey[(size_t)(u0 + r) * KQ + k0 + sc];
      Bs[r * 33 + sc] = Wx[(size_t)(k0 + sc) * G4 + c0 + r];
    }
    __syncthreads();
#pragma unroll
    for (int k = 0; k < 32; ++k) {
      float av[4], bv[4];
#pragma unroll
      for (int i = 0; i < 4; ++i) av[i] = As[(ty * 4 + i) * 33 + k];
#pragma unroll
      for (int j = 0; j < 4; ++j) bv[j] = Bs[(tx * 4 + j) * 33 + k];
#pragma unroll
      for (int i = 0; i < 4; ++i)
#pragma unroll
        for (int j = 0; j < 4; ++j) acc[i][j] += av[i] * bv[j];
    }
    __syncthreads();
  }
#pragma unroll
  for (int i = 0; i < 4; ++i) {
    f32x4 o;
    o.x = acc[i][0]; o.y = acc[i][1]; o.z = acc[i][2]; o.w = acc[i][3];
    *(f32x4*)&Wc[(size_t)(u0 + ty * 4 + i) * G4 + c0 + tx * 4] = o;
  }
}

// ---------------- P4: bkwx[col] = sum_k bk[k] * Wx[k][col] ------------------
__global__ void __launch_bounds__(256) bkwx_k(const float* __restrict__ bk,
                                              const float* __restrict__ Wx,
                                              float* __restrict__ bw) {
  const int col = blockIdx.x * 256 + threadIdx.x;
  float a = 0.f;
  for (int k = 0; k < KQ; ++k) a += bk[k] * Wx[(size_t)k * G4 + col];
  bw[col] = a;
}

// ---------------- K5: persistent recurrence, one sync per step --------------
// z_s = h_{s-1}@Wh + g_{s-1}*(hbar_{s-1}@Wcomb + es*bkwx + Sv[s-1]*Wx[256,:]) + bl
// Sync substrate identical to the R2 kernel that passed: static groups,
// sc0 sc1 (LLC) flags and state everywhere, no XCD probe, no mode switch.
__global__ void __launch_bounds__(NTHR, 2) esbn_scan(
    const float* __restrict__ Wx, const float* __restrict__ Wh,
    const float* __restrict__ bl, const float* __restrict__ Wk,
    const float* __restrict__ bk, const float* __restrict__ Wg,
    const float* __restrict__ bgp, const float* __restrict__ Wmat,
    const float* __restrict__ Sv, const float* __restrict__ Wc,
    const float* __restrict__ bw, float* buf, int* flags,
    float* __restrict__ out) {
  __shared__ short hh[32 * 520];                 // [b*8+u][tau] int16 h history
  __shared__ __align__(16) float st_h[NBG * 512];
  __shared__ __align__(16) float st_q[NBG * 512];
  __shared__ __align__(16) float wrow[NBG * 512];
  __shared__ float wgv[HQ];
  __shared__ __align__(16) float zred[4 * 8 * 4 * 8];
  __shared__ float bl_s[32], e_s[32], l_s[32], c_s[32];
  __shared__ float gg_s[NBG], sv_s[NBG];
  __shared__ float bg_s;

  const int tid = threadIdx.x;
  const int grp = blockIdx.x & 7;   // static group
  const int wg = blockIdx.x >> 3;   // static slot 0..63
  const int b0 = grp * NBG;
  const int dc = tid >> 3;   // 0..31 row chunk
  const int cg = tid & 7;    // col group (4 cols)

  int colg[4];
#pragma unroll
  for (int j = 0; j < 4; ++j) {
    const int c = cg * 4 + j;
    colg[j] = (c >> 3) * HQ + wg * 8 + (c & 7);
  }
  // ---- weights into registers ----
  f32x4 wh[16], wc[16];
#pragma unroll
  for (int i = 0; i < 16; ++i) {
    const int d = (i << 5) + dc;
    wh[i].x = Wh[(size_t)d * G4 + colg[0]];
    wh[i].y = Wh[(size_t)d * G4 + colg[1]];
    wh[i].z = Wh[(size_t)d * G4 + colg[2]];
    wh[i].w = Wh[(size_t)d * G4 + colg[3]];
  }
  if (Wc != nullptr) {
#pragma unroll
    for (int i = 0; i < 16; ++i) {
      const int u = (i << 5) + dc;
      wc[i].x = Wc[(size_t)u * G4 + colg[0]];
      wc[i].y = Wc[(size_t)u * G4 + colg[1]];
      wc[i].z = Wc[(size_t)u * G4 + colg[2]];
      wc[i].w = Wc[(size_t)u * G4 + colg[3]];
    }
    if (tid < 32) {
      const int gc = (tid >> 3) * HQ + wg * 8 + (tid & 7);
      e_s[tid] = bw[gc];
    }
  } else {
    // fallback: compute Wcomb slice in-kernel (ws too small for a buffer)
#pragma unroll
    for (int i = 0; i < 16; ++i) { wc[i].x = wc[i].y = wc[i].z = wc[i].w = 0.f; }
    f32x4 e4; e4.x = e4.y = e4.z = e4.w = 0.f;
    for (int k = 0; k < KQ; ++k) {
      f32x4 wxk;
      wxk.x = Wx[(size_t)k * G4 + colg[0]];
      wxk.y = Wx[(size_t)k * G4 + colg[1]];
      wxk.z = Wx[(size_t)k * G4 + colg[2]];
      wxk.w = Wx[(size_t)k * G4 + colg[3]];
      e4 += bk[k] * wxk;
#pragma unroll
      for (int i = 0; i < 16; ++i) wc[i] += Wk[(size_t)((i << 5) + dc) * KQ + k] * wxk;
    }
    if (dc == 0) {
      e_s[cg * 4 + 0] = e4.x; e_s[cg * 4 + 1] = e4.y;
      e_s[cg * 4 + 2] = e4.z; e_s[cg * 4 + 3] = e4.w;
    }
  }
  if (tid < 32) {
    const int gc = (tid >> 3) * HQ + wg * 8 + (tid & 7);
    bl_s[tid] = bl[gc];
    l_s[tid] = Wx[(size_t)256 * G4 + gc];
    c_s[tid] = 0.f;
  }
  for (int i = tid; i < 32 * 520; i += NTHR) hh[i] = 0;
  for (int i = tid; i < HQ; i += NTHR) wgv[i] = Wg[i];
  if (tid == 0) bg_s = bgp[0];
  __syncthreads();

  int* fx = flags + grp * 64;
  const int yb = tid >> 6;         // batch 0..3
  const int yu = (tid >> 3) & 7;   // unit 0..7
  const int ytc = tid & 7;         // tau chunk
  const float invS = 1.f / 32767.f;

  for (int s = 0; s < TQ; ++s) {
    const int p = s & 1, pn = p ^ 1;
    // A: stage softmax row s into wrow (zero-pad tau >= s) + Sv[s-1]
    {
#pragma unroll
      for (int k = 0; k < 2; ++k) {
        const int f = k * 256 + tid;
        const int b = f >> 7, off = (f & 127) << 2;
        const float* src = Wmat + ((size_t)(b0 + b) * TQ + s) * TQ + off;
        f32x4 v = *(const f32x4*)src;
        v.x = (off + 0 < s) ? v.x : 0.f;
        v.y = (off + 1 < s) ? v.y : 0.f;
        v.z = (off + 2 < s) ? v.z : 0.f;
        v.w = (off + 3 < s) ? v.w : 0.f;
        *(f32x4*)&wrow[b * 512 + off] = v;
      }
      if (tid < 4) sv_s[tid] = (s >= 1) ? Sv[(size_t)(b0 + tid) * TQ + (s - 1)] : 0.f;
    }
    __syncthreads();  // b1
    // B: pre-dot hbar_s (history part; hh[s-1] still zero here by design)
    float pre = 0.f;
    if (s > 0 && s < TQ - 1) {
      const short2* hp = (const short2*)&hh[(yb * 8 + yu) * 520];
      const float2* wp = (const float2*)&wrow[yb * 512];
#pragma unroll
      for (int j = 0; j < 32; ++j) {
        const short2 hv2 = hp[ytc + 8 * j];
        const float2 w2 = wp[ytc + 8 * j];
        pre += w2.x * (float)hv2.x + w2.y * (float)hv2.y;
      }
      pre += __shfl_xor(pre, 1);
      pre += __shfl_xor(pre, 2);
      pre += __shfl_xor(pre, 4);
      pre *= invS;
    }
    // C: wait for h_{s-1} + hbar_{s-1}
    wg_wait(fx, s);
    // D: stage h and hbar from broadcast buffer (batched loads, one waitcnt)
    {
      const float* base = buf + (size_t)(p * BQ + b0) * PROW;
      const int off = tid << 2;
      f32x4 v[4];
#pragma unroll
      for (int k = 0; k < 4; ++k) v[k] = ldx4(base + (size_t)k * PROW + off);
      asm volatile("s_waitcnt vmcnt(0)"
                   : "+v"(v[0]), "+v"(v[1]), "+v"(v[2]), "+v"(v[3]) :: "memory");
#pragma unroll
      for (int k = 0; k < 4; ++k) {
        if (tid < 128) *(f32x4*)&st_h[k * 512 + off] = v[k];
        else *(f32x4*)&st_q[k * 512 + off - 512] = v[k];
      }
    }
    __syncthreads();  // b2
    // D2: append h_{s-1} to history; finalize + publish hbar_s
    if (ytc == 0) {
      const float hprev = st_h[yb * 512 + wg * 8 + yu];
      if (s > 0) {
        hh[(yb * 8 + yu) * 520 + (s - 1)] = (short)__float2int_rn(hprev * 32767.f);
        if (s < TQ - 1) {
          const float hb = pre + wrow[yb * 512 + (s - 1)] * hprev;
          st_agent(buf + (size_t)(pn * BQ + b0 + yb) * PROW + 512 + wg * 8 + yu, hb);
        }
      } else if (s < TQ - 1) {
        st_agent(buf + (size_t)(pn * BQ + b0 + yb) * PROW + 512 + wg * 8 + yu, 0.f);
      }
    }
    // E: g_{s-1} = sigmoid(h_{s-1} . Wg + bg), one wave per batch
    {
      float a = 0.f;
      const int lt = tid & 63;
#pragma unroll
      for (int k = 0; k < 8; ++k) {
        const int u = lt + (k << 6);
        a += st_h[yb * 512 + u] * wgv[u];
      }
#pragma unroll
      for (int m = 1; m <= 32; m <<= 1) a += __shfl_xor(a, m);
      if (lt == 0) gg_s[yb] = sigm(a + bg_s);
    }
    // F: dual GEMM (h@Wh, hbar@Wcomb)
    f32x4 aH[NBG], aQ[NBG];
#pragma unroll
    for (int b = 0; b < NBG; ++b) {
      aH[b].x = aH[b].y = aH[b].z = aH[b].w = 0.f;
      aQ[b].x = aQ[b].y = aQ[b].z = aQ[b].w = 0.f;
    }
#pragma unroll
    for (int i = 0; i < 16; ++i) {
      const int d = (i << 5) + dc;
      const f32x4 w1 = wh[i], w2 = wc[i];
#pragma unroll
      for (int b = 0; b < NBG; ++b) {
        aH[b] += st_h[b * 512 + d] * w1;
        aQ[b] += st_q[b * 512 + d] * w2;
      }
    }
#pragma unroll
    for (int m = 8; m <= 32; m <<= 1) {
#pragma unroll
      for (int b = 0; b < NBG; ++b) {
        aH[b].x += __shfl_xor(aH[b].x, m); aH[b].y += __shfl_xor(aH[b].y, m);
        aH[b].z += __shfl_xor(aH[b].z, m); aH[b].w += __shfl_xor(aH[b].w, m);
        aQ[b].x += __shfl_xor(aQ[b].x, m); aQ[b].y += __shfl_xor(aQ[b].y, m);
        aQ[b].z += __shfl_xor(aQ[b].z, m); aQ[b].w += __shfl_xor(aQ[b].w, m);
      }
    }
    {
      const int lt = tid & 63;
      if (lt < 8) {
        const int wv = tid >> 6;
#pragma unroll
        for (int b = 0; b < NBG; ++b) {
          *(f32x4*)&zred[((wv * 8 + lt) * 4 + b) * 8] = aH[b];
          *(f32x4*)&zred[((wv * 8 + lt) * 4 + b) * 8 + 4] = aQ[b];
        }
      }
    }
    __syncthreads();  // b3
    // G: z assembly + LSTM pointwise (thread = (b,u))
    if (tid < 32) {
      const int b = tid >> 3, u = tid & 7;
      const float g = (s > 0) ? gg_s[b] : 0.f;
      const float es = (s >= 2) ? 1.f : 0.f;
      const float sv = sv_s[b];
      float zg[4];
#pragma unroll
      for (int gi = 0; gi < 4; ++gi) {
        const int c = gi * 8 + u, cgi = c >> 2, comp = c & 3;
        float sH = 0.f, sQ = 0.f;
#pragma unroll
        for (int wv = 0; wv < 4; ++wv) {
          sH += zred[((wv * 8 + cgi) * 4 + b) * 8 + comp];
          sQ += zred[((wv * 8 + cgi) * 4 + b) * 8 + 4 + comp];
        }
        zg[gi] = sH + g * (sQ + es * e_s[c] + sv * l_s[c]) + bl_s[c];
      }
      const float gi_ = sigm(zg[0]);
      const float gf = sigm(zg[1]);
      const float go = sigm(zg[3]);
      const float cn = gf * c_s[tid] + gi_ * tanhf(zg[2]);
      const float hv = go * tanhf(cn);
      c_s[tid] = cn;
      if (s == TQ - 1) {
        out[(size_t)(b0 + b) * HQ + wg * 8 + u] = hv;
      } else {
        st_agent(buf + (size_t)(pn * BQ + b0 + b) * PROW + wg * 8 + u, hv);
      }
    }
    if (s == TQ - 1) break;
    // H: publish
    waitcnt0();
    __syncthreads();  // b4
    if (tid == 0) {
      int* fp = &fx[wg];
      const int val = s + 1;
      asm volatile("global_store_dword %0, %1, off sc0 sc1" :: "v"(fp), "v"(val) : "memory");
    }
  }
}

extern "C" void kernel_launch(void* const* d_in, const int* in_sizes, int n_in,
                              void* d_out, int out_size, void* d_ws, size_t ws_size,
                              hipStream_t stream) {
  (void)in_sizes; (void)n_in; (void)out_size;
  const float* X  = (const float*)d_in[0];
  const float* Wx = (const float*)d_in[1];
  const float* Wh = (const float*)d_in[2];
  const float* bl = (const float*)d_in[3];
  const float* Wk = (const float*)d_in[4];
  const float* bk = (const float*)d_in[5];
  const float* Wg = (const float*)d_in[6];
  const float* bg = (const float*)d_in[7];
  const float* cg = (const float*)d_in[8];
  const float* cb = (const float*)d_in[9];
  float* out = (float*)d_out;
  float* ws = (float*)d_ws;

  size_t off = 8388608;                 // Gm = ws[0 .. 8M)
  float* Gm = ws;
  float* Wc = nullptr;
  float* bw = nullptr;
  const size_t need_wc = (size_t)(8388608 + 1048576 + 2048 + 16384 + 65792 + 512) * 4;
  const bool havewc = ws_size >= need_wc;
  if (havewc) { Wc = ws + off; off += 1048576; bw = ws + off; off += 2048; }
  float* Sv = ws + off; off += 16384;
  float* buf = ws + off; off += 65792;
  int* flags = (int*)(ws + off);        // 512 flags

  // zero Sv | buf | flags (contiguous)
  hipMemsetAsync(Sv, 0, (size_t)(16384 + 65792 + 512) * 4, stream);
  gram_k<<<dim3(36, BQ), dim3(256), 0, stream>>>(X, Gm);
  smax_k<<<dim3(TQ - 1, BQ), dim3(256), 0, stream>>>(Gm, Sv, cg, cb);
  if (havewc) {
    wcomb_k<<<dim3(32, 8), dim3(256), 0, stream>>>(Wk, Wx, Wc);
    bkwx_k<<<dim3(8), dim3(256), 0, stream>>>(bk, Wx, bw);
  }

  void* args[] = {(void*)&Wx, (void*)&Wh, (void*)&bl, (void*)&Wk, (void*)&bk,
                  (void*)&Wg, (void*)&bg, (void*)&Gm, (void*)&Sv, (void*)&Wc,
                  (void*)&bw, (void*)&buf, (void*)&flags, (void*)&out};
  hipError_t e = hipLaunchCooperativeKernel((const void*)esbn_scan, dim3(NWG),
                                            dim3(NTHR), args, 0, stream);
  if (e != hipSuccess) {
    esbn_scan<<<dim3(NWG), dim3(NTHR), 0, stream>>>(Wx, Wh, bl, Wk, bk, Wg, bg,
                                                    Gm, Sv, Wc, bw, buf, flags,
                                                    out);
  }
}

// Round 6
// 4982.836 us; speedup vs baseline: 1.2770x; 1.2770x over previous
//
#include <hip/hip_runtime.h>
#include <math.h>

#define BQ 32
#define TQ 512
#define DQ 768
#define KQ 256
#define HQ 512
#define G4 2048
#define NWG 512    // 8 groups x 64 WGs
#define NTHR 256
#define NBG 4      // batches per group

typedef float f32x4 __attribute__((ext_vector_type(4)));
typedef int i32x4 __attribute__((ext_vector_type(4)));

__device__ __forceinline__ void waitcnt0() {
  asm volatile("s_waitcnt vmcnt(0) lgkmcnt(0)" ::: "memory");
}
__device__ __forceinline__ void st_short(short* p, int v) {
  asm volatile("global_store_short %0, %1, off sc0 sc1" :: "v"(p), "v"(v) : "memory");
}
__device__ __forceinline__ int ld_flag(const int* p) {
  int v;
  asm volatile("global_load_dword %0, %1, off sc0 sc1\ns_waitcnt vmcnt(0)"
               : "=v"(v) : "v"(p) : "memory");
  return v;
}
__device__ __forceinline__ i32x4 ldx4i(const void* p) {
  i32x4 v;
  asm volatile("global_load_dwordx4 %0, %1, off sc0 sc1" : "=v"(v) : "v"(p) : "memory");
  return v;
}
__device__ __forceinline__ void wg_wait(const int* flags, int target) {
  if (threadIdx.x < 64) {
    for (;;) {
      int v = ld_flag(flags + threadIdx.x);
      if (__all(v >= target)) break;
      __builtin_amdgcn_s_sleep(1);
    }
  }
  __syncthreads();
}
__device__ __forceinline__ float sigm(float x) { return 1.f / (1.f + __expf(-x)); }

// ---------------- P1: Gram matrix G[b][t][tau] = x_t . x_tau ----------------
__global__ void __launch_bounds__(256) gram_k(const float* __restrict__ X,
                                              float* __restrict__ Gm) {
  __shared__ __align__(16) float As[64 * 33];
  __shared__ __align__(16) float Bs[64 * 33];
  const int bid = blockIdx.x;
  const int b = blockIdx.y;
  int I = 0, base = 0;
  while (base + I + 1 <= bid) { base += I + 1; ++I; }
  const int J = bid - base;
  const int t0 = I * 64, u0 = J * 64;
  const float* Xb = X + (size_t)b * TQ * DQ;
  const int ty = threadIdx.x >> 4, tx = threadIdx.x & 15;
  const int sc = threadIdx.x & 31, sr = threadIdx.x >> 5;
  float acc[4][4];
#pragma unroll
  for (int i = 0; i < 4; ++i)
#pragma unroll
    for (int j = 0; j < 4; ++j) acc[i][j] = 0.f;
  for (int k0 = 0; k0 < DQ; k0 += 32) {
#pragma unroll
    for (int rr = 0; rr < 8; ++rr) {
      const int r = rr * 8 + sr;
      As[r * 33 + sc] = Xb[(size_t)(t0 + r) * DQ + k0 + sc];
      Bs[r * 33 + sc] = Xb[(size_t)(u0 + r) * DQ + k0 + sc];
    }
    __syncthreads();
#pragma unroll
    for (int k = 0; k < 32; ++k) {
      float av[4], bv[4];
#pragma unroll
      for (int i = 0; i < 4; ++i) av[i] = As[(ty * 4 + i) * 33 + k];
#pragma unroll
      for (int j = 0; j < 4; ++j) bv[j] = Bs[(tx * 4 + j) * 33 + k];
#pragma unroll
      for (int i = 0; i < 4; ++i)
#pragma unroll
        for (int j = 0; j < 4; ++j) acc[i][j] += av[i] * bv[j];
    }
    __syncthreads();
  }
  float* gb = Gm + (size_t)b * TQ * TQ;
#pragma unroll
  for (int i = 0; i < 4; ++i) {
    f32x4 o;
    o.x = acc[i][0]; o.y = acc[i][1]; o.z = acc[i][2]; o.w = acc[i][3];
    *(f32x4*)&gb[(size_t)(t0 + ty * 4 + i) * TQ + u0 + tx * 4] = o;
  }
}

// ---------------- P2: row softmax (tau < t) in place + S[b][t] --------------
__global__ void __launch_bounds__(256) smax_k(float* __restrict__ Gm,
                                              float* __restrict__ Sv,
                                              const float* __restrict__ cgp,
                                              const float* __restrict__ cbp) {
  const int t = blockIdx.x + 1;
  const int b = blockIdx.y;
  const int tid = threadIdx.x;
  const int lane = tid & 63;
  const int wv = tid >> 6;
  __shared__ float row[TQ];
  __shared__ float r1[4], r2[4], r3[4];
  float* R = Gm + ((size_t)b * TQ + t) * TQ;
  const float cg = cgp[0], cb = cbp[0];
  for (int i = tid; i < t; i += 256) row[i] = R[i];
  __syncthreads();
  float m = -3e38f;
  for (int i = tid; i < t; i += 256) m = fmaxf(m, row[i]);
#pragma unroll
  for (int k = 1; k < 64; k <<= 1) m = fmaxf(m, __shfl_xor(m, k));
  if (lane == 0) r1[wv] = m;
  __syncthreads();
  m = fmaxf(fmaxf(r1[0], r1[1]), fmaxf(r1[2], r1[3]));
  float s = 0.f, sck = 0.f;
  for (int i = tid; i < t; i += 256) {
    const float r = row[i];
    const float e = __expf(r - m);
    const float ck = 1.f / (1.f + __expf(-(r * cg + cb)));
    row[i] = e; s += e; sck += e * ck;
  }
#pragma unroll
  for (int k = 1; k < 64; k <<= 1) { s += __shfl_xor(s, k); sck += __shfl_xor(sck, k); }
  if (lane == 0) { r2[wv] = s; r3[wv] = sck; }
  __syncthreads();
  s = r2[0] + r2[1] + r2[2] + r2[3];
  sck = r3[0] + r3[1] + r3[2] + r3[3];
  const float inv = 1.f / s;
  for (int i = tid; i < t; i += 256) R[i] = row[i] * inv;
  if (tid == 0) Sv[(size_t)b * TQ + t] = sck * inv;
}

// ---------------- P3: Wcomb[u][col] = sum_k Wkey[u][k] * Wx[k][col] ---------
__global__ void __launch_bounds__(256) wcomb_k(const float* __restrict__ Wkey,
                                               const float* __restrict__ Wx,
                                               float* __restrict__ Wc) {
  __shared__ __align__(16) float As[64 * 33];  // [u][k]
  __shared__ __align__(16) float Bs[64 * 33];  // [col][k]
  const int c0 = blockIdx.x * 64, u0 = blockIdx.y * 64;
  const int ty = threadIdx.x >> 4, tx = threadIdx.x & 15;
  const int sc = threadIdx.x & 31, sr = threadIdx.x >> 5;
  float acc[4][4];
#pragma unroll
  for (int i = 0; i < 4; ++i)
#pragma unroll
    for (int j = 0; j < 4; ++j) acc[i][j] = 0.f;
  for (int k0 = 0; k0 < KQ; k0 += 32) {
#pragma unroll
    for (int rr = 0; rr < 8; ++rr) {
      const int r = rr * 8 + sr;
      As[r * 33 + sc] = Wkey[(size_t)(u0 + r) * KQ + k0 + sc];
      Bs[r * 33 + sc] = Wx[(size_t)(k0 + sc) * G4 + c0 + r];
    }
    __syncthreads();
#pragma unroll
    for (int k = 0; k < 32; ++k) {
      float av[4], bv[4];
#pragma unroll
      for (int i = 0; i < 4; ++i) av[i] = As[(ty * 4 + i) * 33 + k];
#pragma unroll
      for (int j = 0; j < 4; ++j) bv[j] = Bs[(tx * 4 + j) * 33 + k];
#pragma unroll
      for (int i = 0; i < 4; ++i)
#pragma unroll
        for (int j = 0; j < 4; ++j) acc[i][j] += av[i] * bv[j];
    }
    __syncthreads();
  }
#pragma unroll
  for (int i = 0; i < 4; ++i) {
    f32x4 o;
    o.x = acc[i][0]; o.y = acc[i][1]; o.z = acc[i][2]; o.w = acc[i][3];
    *(f32x4*)&Wc[(size_t)(u0 + ty * 4 + i) * G4 + c0 + tx * 4] = o;
  }
}

// ---------------- P4: bkwx[col] = sum_k bk[k] * Wx[k][col] ------------------
__global__ void __launch_bounds__(256) bkwx_k(const float* __restrict__ bk,
                                              const float* __restrict__ Wx,
                                              float* __restrict__ bw) {
  const int col = blockIdx.x * 256 + threadIdx.x;
  float a = 0.f;
  for (int k = 0; k < KQ; ++k) a += bk[k] * Wx[(size_t)k * G4 + col];
  bw[col] = a;
}

// ---------------- K5: persistent recurrence, one sync per step --------------
// z_s = h_{s-1}@Wh + g_{s-1}*(hbar_{s-1}@Wcomb + es*bkwx + Sv[s-1]*Wx[256,:]) + bl
// h / hbar broadcast as int16 (scale 32767); invS folded into weight regs.
// Sync substrate = proven R2/R5: static groups, sc0 sc1 flags/pub everywhere.
__global__ void __launch_bounds__(NTHR, 2) esbn_scan(
    const float* __restrict__ Wx, const float* __restrict__ Wh,
    const float* __restrict__ bl, const float* __restrict__ Wk,
    const float* __restrict__ bk, const float* __restrict__ Wg,
    const float* __restrict__ bgp, const float* __restrict__ Wmat,
    const float* __restrict__ Sv, const float* __restrict__ Wc,
    const float* __restrict__ bw, short* sbuf, int* flags,
    float* __restrict__ out) {
  __shared__ short hh[32 * 520];                  // [b*8+u][tau] int16 history
  __shared__ __align__(16) float st_h[NBG * 512]; // raw (int-valued) h
  __shared__ __align__(16) float st_q[NBG * 512]; // raw (int-valued) hbar
  __shared__ float wgv[HQ];                       // Wg * invS
  __shared__ __align__(16) float zred[1024];
  __shared__ float bl_s[32], e_s[32], l_s[32], c_s[32];
  __shared__ float gg_s[NBG], sv_s[NBG];
  __shared__ float bg_s;

  const int tid = threadIdx.x;
  const int grp = blockIdx.x & 7;   // static group
  const int wg = blockIdx.x >> 3;   // static slot 0..63
  const int b0 = grp * NBG;
  const int dc = tid >> 3;   // 0..31 d-chunk (16 contiguous d each)
  const int cg = tid & 7;    // col group (4 cols)
  const float invS = 1.f / 32767.f;

  int colg[4];
#pragma unroll
  for (int j = 0; j < 4; ++j) {
    const int c = cg * 4 + j;
    colg[j] = (c >> 3) * HQ + wg * 8 + (c & 7);
  }
  // ---- weights into registers (d = dc*16 + i), pre-scaled by invS ----
  f32x4 wh[16], wc[16];
#pragma unroll
  for (int i = 0; i < 16; ++i) {
    const int d = dc * 16 + i;
    wh[i].x = Wh[(size_t)d * G4 + colg[0]] * invS;
    wh[i].y = Wh[(size_t)d * G4 + colg[1]] * invS;
    wh[i].z = Wh[(size_t)d * G4 + colg[2]] * invS;
    wh[i].w = Wh[(size_t)d * G4 + colg[3]] * invS;
  }
  if (Wc != nullptr) {
#pragma unroll
    for (int i = 0; i < 16; ++i) {
      const int u = dc * 16 + i;
      wc[i].x = Wc[(size_t)u * G4 + colg[0]] * invS;
      wc[i].y = Wc[(size_t)u * G4 + colg[1]] * invS;
      wc[i].z = Wc[(size_t)u * G4 + colg[2]] * invS;
      wc[i].w = Wc[(size_t)u * G4 + colg[3]] * invS;
    }
    if (tid < 32) {
      const int gc = (tid >> 3) * HQ + wg * 8 + (tid & 7);
      e_s[tid] = bw[gc];
    }
  } else {
#pragma unroll
    for (int i = 0; i < 16; ++i) { wc[i].x = wc[i].y = wc[i].z = wc[i].w = 0.f; }
    f32x4 e4; e4.x = e4.y = e4.z = e4.w = 0.f;
    for (int k = 0; k < KQ; ++k) {
      f32x4 wxk;
      wxk.x = Wx[(size_t)k * G4 + colg[0]];
      wxk.y = Wx[(size_t)k * G4 + colg[1]];
      wxk.z = Wx[(size_t)k * G4 + colg[2]];
      wxk.w = Wx[(size_t)k * G4 + colg[3]];
      e4 += bk[k] * wxk;
#pragma unroll
      for (int i = 0; i < 16; ++i) wc[i] += Wk[(size_t)(dc * 16 + i) * KQ + k] * wxk;
    }
#pragma unroll
    for (int i = 0; i < 16; ++i) {
      wc[i].x *= invS; wc[i].y *= invS; wc[i].z *= invS; wc[i].w *= invS;
    }
    if (dc == 0) {
      e_s[cg * 4 + 0] = e4.x; e_s[cg * 4 + 1] = e4.y;
      e_s[cg * 4 + 2] = e4.z; e_s[cg * 4 + 3] = e4.w;
    }
  }
  if (tid < 32) {
    const int gc = (tid >> 3) * HQ + wg * 8 + (tid & 7);
    bl_s[tid] = bl[gc];
    l_s[tid] = Wx[(size_t)256 * G4 + gc];
    c_s[tid] = 0.f;
  }
  for (int i = tid; i < 32 * 520; i += NTHR) hh[i] = 0;
  for (int i = tid; i < HQ; i += NTHR) wgv[i] = Wg[i] * invS;
  if (tid == 0) bg_s = bgp[0];
  __syncthreads();

  int* fx = flags + grp * 64;
  const int yb = tid >> 6;         // batch 0..3
  const int yu = (tid >> 3) & 7;   // unit 0..7
  const int ytc = tid & 7;         // tau chunk
  const int lt = tid & 63;

  for (int s = 0; s < TQ; ++s) {
    const int p = s & 1, pn = p ^ 1;
    // B': pre-wait work — hbar pre-dot straight from Gm (hh zeros mask tau>=s-1)
    float pre = 0.f;
    if (s > 0 && s < TQ - 1) {
      const float2* wp = (const float2*)(Wmat + ((size_t)(b0 + yb) * TQ + s) * TQ);
      const short2* hp = (const short2*)&hh[(yb * 8 + yu) * 520];
#pragma unroll
      for (int j = 0; j < 32; ++j) {
        const short2 h2 = hp[ytc + 8 * j];
        const float2 w2 = wp[ytc + 8 * j];
        pre += w2.x * (float)h2.x + w2.y * (float)h2.y;
      }
      pre += __shfl_xor(pre, 1);
      pre += __shfl_xor(pre, 2);
      pre += __shfl_xor(pre, 4);
      pre *= invS;
    }
    const float gprev =
        (s > 0) ? Wmat[((size_t)(b0 + yb) * TQ + s) * TQ + (s - 1)] : 0.f;
    if (tid < 4)
      sv_s[tid] = (s >= 1) ? Sv[(size_t)(b0 + tid) * TQ + (s - 1)] : 0.f;
    // C: wait for h_{s-1} + hbar_{s-1} (wave0 polls only)
    wg_wait(fx, s);
    // D: stage int16 slot -> raw f32 in LDS (2 dwordx4 per thread)
    {
      const short* sp = sbuf + (size_t)(grp * 2 + p) * 4096 + tid * 16;
      i32x4 a = ldx4i(sp);
      i32x4 b2 = ldx4i(sp + 8);
      asm volatile("s_waitcnt vmcnt(0)" : "+v"(a), "+v"(b2) :: "memory");
      float vals[16];
#pragma unroll
      for (int k = 0; k < 4; ++k) {
        const int d0 = a[k];
        vals[2 * k] = (float)(short)d0;
        vals[2 * k + 1] = (float)(d0 >> 16);
      }
#pragma unroll
      for (int k = 0; k < 4; ++k) {
        const int d0 = b2[k];
        vals[8 + 2 * k] = (float)(short)d0;
        vals[8 + 2 * k + 1] = (float)(d0 >> 16);
      }
      float* dst = (tid < 128) ? &st_h[tid * 16] : &st_q[tid * 16 - 2048];
#pragma unroll
      for (int k = 0; k < 4; ++k) {
        f32x4 o;
        o.x = vals[4 * k]; o.y = vals[4 * k + 1];
        o.z = vals[4 * k + 2]; o.w = vals[4 * k + 3];
        *(f32x4*)(dst + 4 * k) = o;
      }
    }
    __syncthreads();  // b2
    // D2: append h_{s-1} to history; finalize + publish hbar_s (int16)
    if (ytc == 0) {
      const float hraw = st_h[yb * 512 + wg * 8 + yu];
      if (s > 0) {
        hh[(yb * 8 + yu) * 520 + (s - 1)] = (short)__float2int_rn(hraw);
        if (s < TQ - 1) {
          const float hb = pre + gprev * (hraw * invS);
          st_short(sbuf + (size_t)(grp * 2 + pn) * 4096 + 2048 + yb * 512 + wg * 8 + yu,
                   __float2int_rn(hb * 32767.f));
        }
      }
      // s == 0: slot pn hbar region is zero from memset — nothing to publish
    }
    // E: g_{s-1} = sigmoid(h . Wg + bg)  (st_h raw x wgv pre-scaled)
    {
      float a = 0.f;
#pragma unroll
      for (int k = 0; k < 8; ++k) {
        const int u = lt + (k << 6);
        a += st_h[yb * 512 + u] * wgv[u];
      }
#pragma unroll
      for (int m = 1; m <= 32; m <<= 1) a += __shfl_xor(a, m);
      if (lt == 0) gg_s[yb] = sigm(a + bg_s);
    }
    // F: dual GEMM (h@Wh, hbar@Wcomb) — b128 LDS reads, d = dc*16+i
    f32x4 aH[NBG], aQ[NBG];
#pragma unroll
    for (int b = 0; b < NBG; ++b) {
      aH[b].x = aH[b].y = aH[b].z = aH[b].w = 0.f;
      aQ[b].x = aQ[b].y = aQ[b].z = aQ[b].w = 0.f;
    }
#pragma unroll
    for (int i4 = 0; i4 < 4; ++i4) {
#pragma unroll
      for (int b = 0; b < NBG; ++b) {
        const f32x4 h4 = *(const f32x4*)&st_h[b * 512 + dc * 16 + i4 * 4];
        const f32x4 q4 = *(const f32x4*)&st_q[b * 512 + dc * 16 + i4 * 4];
#pragma unroll
        for (int c = 0; c < 4; ++c) {
          aH[b] += h4[c] * wh[i4 * 4 + c];
          aQ[b] += q4[c] * wc[i4 * 4 + c];
        }
      }
    }
#pragma unroll
    for (int m = 8; m <= 32; m <<= 1) {
#pragma unroll
      for (int b = 0; b < NBG; ++b) {
        aH[b].x += __shfl_xor(aH[b].x, m); aH[b].y += __shfl_xor(aH[b].y, m);
        aH[b].z += __shfl_xor(aH[b].z, m); aH[b].w += __shfl_xor(aH[b].w, m);
        aQ[b].x += __shfl_xor(aQ[b].x, m); aQ[b].y += __shfl_xor(aQ[b].y, m);
        aQ[b].z += __shfl_xor(aQ[b].z, m); aQ[b].w += __shfl_xor(aQ[b].w, m);
      }
    }
    if (lt < 8) {
      const int wv = tid >> 6;
#pragma unroll
      for (int b = 0; b < NBG; ++b) {
        *(f32x4*)&zred[((wv * 8 + lt) * 4 + b) * 8] = aH[b];
        *(f32x4*)&zred[((wv * 8 + lt) * 4 + b) * 8 + 4] = aQ[b];
      }
    }
    __syncthreads();  // b3
    // G: z assembly + LSTM pointwise (thread = (b,u)); publish h int16
    if (tid < 32) {
      const int b = tid >> 3, u = tid & 7;
      const float g = (s > 0) ? gg_s[b] : 0.f;
      const float es = (s >= 2) ? 1.f : 0.f;
      const float sv = sv_s[b];
      float zg[4];
#pragma unroll
      for (int gi = 0; gi < 4; ++gi) {
        const int c = gi * 8 + u, cgi = c >> 2, comp = c & 3;
        float sH = 0.f, sQ = 0.f;
#pragma unroll
        for (int wv = 0; wv < 4; ++wv) {
          sH += zred[((wv * 8 + cgi) * 4 + b) * 8 + comp];
          sQ += zred[((wv * 8 + cgi) * 4 + b) * 8 + 4 + comp];
        }
        zg[gi] = sH + g * (sQ + es * e_s[c] + sv * l_s[c]) + bl_s[c];
      }
      const float gi_ = sigm(zg[0]);
      const float gf = sigm(zg[1]);
      const float go = sigm(zg[3]);
      const float cn = gf * c_s[tid] + gi_ * tanhf(zg[2]);
      const float hv = go * tanhf(cn);
      c_s[tid] = cn;
      if (s == TQ - 1) {
        out[(size_t)(b0 + b) * HQ + wg * 8 + u] = hv;
      } else {
        st_short(sbuf + (size_t)(grp * 2 + pn) * 4096 + b * 512 + wg * 8 + u,
                 __float2int_rn(hv * 32767.f));
      }
    }
    if (s == TQ - 1) break;
    // H: publish flag
    waitcnt0();
    __syncthreads();  // b4
    if (tid == 0) {
      int* fp = &fx[wg];
      const int val = s + 1;
      asm volatile("global_store_dword %0, %1, off sc0 sc1" :: "v"(fp), "v"(val) : "memory");
    }
  }
}

extern "C" void kernel_launch(void* const* d_in, const int* in_sizes, int n_in,
                              void* d_out, int out_size, void* d_ws, size_t ws_size,
                              hipStream_t stream) {
  (void)in_sizes; (void)n_in; (void)out_size;
  const float* X  = (const float*)d_in[0];
  const float* Wx = (const float*)d_in[1];
  const float* Wh = (const float*)d_in[2];
  const float* bl = (const float*)d_in[3];
  const float* Wk = (const float*)d_in[4];
  const float* bk = (const float*)d_in[5];
  const float* Wg = (const float*)d_in[6];
  const float* bg = (const float*)d_in[7];
  const float* cg = (const float*)d_in[8];
  const float* cb = (const float*)d_in[9];
  float* out = (float*)d_out;
  float* ws = (float*)d_ws;

  size_t off = 8388608;                 // Gm = ws[0 .. 8M)
  float* Gm = ws;
  float* Wc = nullptr;
  float* bw = nullptr;
  const size_t need_wc = (size_t)(8388608 + 1048576 + 2048 + 16384 + 32768 + 512) * 4;
  const bool havewc = ws_size >= need_wc;
  if (havewc) { Wc = ws + off; off += 1048576; bw = ws + off; off += 2048; }
  float* Sv = ws + off; off += 16384;
  short* sbuf = (short*)(ws + off); off += 32768;   // 65536 int16 (128 KB)
  int* flags = (int*)(ws + off);                    // 512 flags

  // zero Sv | sbuf | flags (one contiguous region)
  hipMemsetAsync(Sv, 0, (size_t)(16384 + 32768 + 512) * 4, stream);
  gram_k<<<dim3(36, BQ), dim3(256), 0, stream>>>(X, Gm);
  smax_k<<<dim3(TQ - 1, BQ), dim3(256), 0, stream>>>(Gm, Sv, cg, cb);
  if (havewc) {
    wcomb_k<<<dim3(32, 8), dim3(256), 0, stream>>>(Wk, Wx, Wc);
    bkwx_k<<<dim3(8), dim3(256), 0, stream>>>(bk, Wx, bw);
  }

  void* args[] = {(void*)&Wx, (void*)&Wh, (void*)&bl, (void*)&Wk, (void*)&bk,
                  (void*)&Wg, (void*)&bg, (void*)&Gm, (void*)&Sv, (void*)&Wc,
                  (void*)&bw, (void*)&sbuf, (void*)&flags, (void*)&out};
  hipError_t e = hipLaunchCooperativeKernel((const void*)esbn_scan, dim3(NWG),
                                            dim3(NTHR), args, 0, stream);
  if (e != hipSuccess) {
    esbn_scan<<<dim3(NWG), dim3(NTHR), 0, stream>>>(Wx, Wh, bl, Wk, bk, Wg, bg,
                                                    Gm, Sv, Wc, bw, sbuf, flags,
                                                    out);
  }
}